// Round 5
// baseline (386.784 us; speedup 1.0000x reference)
//
#include <hip/hip_runtime.h>
#include <hip/hip_bf16.h>

#define HW    16384   // 128*128
#define IMW   128
#define IMH   128
#define CIN   256
#define CR    64
#define G     16
#define GC    16

typedef __attribute__((ext_vector_type(8))) short short8;
typedef __attribute__((ext_vector_type(4))) float floatx4;

static __device__ __forceinline__ short f2bf(float f) {
  union { float f; unsigned u; } v; v.f = f;
  unsigned r = v.u + 0x7fffu + ((v.u >> 16) & 1u);   // RNE
  return (short)(r >> 16);
}
static __device__ __forceinline__ float bf2f(short s) {
  union { unsigned u; float f; } v; v.u = ((unsigned)(unsigned short)s) << 16;
  return v.f;
}

// ---------------------------------------------------------------------------
// K0: weight prep.
//   blocks 0..63   : w1 (fp32 [64][256]) -> bf16 w1b (lives in dead y2b head)
//   blocks 64..127 : w2 (fp32 [144][64]) -> w2p  bf16 [8 gp][32 rows][64]
//                    (rows 0..17 = w2 rows gp*18..gp*18+17, rows 18..31 = 0)
//   blocks 128..191: same -> w2pr bf16 residual (w2 - bf16(w2), re-quantized;
//                    w2p + w2pr ~= w2 to ~2^-17 rel — verified in round 3)
// ---------------------------------------------------------------------------
__global__ __launch_bounds__(256) void k_cvt(const float* __restrict__ w1,
                                             const float* __restrict__ w2,
                                             short* __restrict__ w1b,
                                             short* __restrict__ w2p,
                                             short* __restrict__ w2pr) {
  const int blk = blockIdx.x;
  const int tid = threadIdx.x;
  if (blk < 64) {
    const int i = blk * 256 + tid;                   // 16384 elements
    w1b[i] = f2bf(w1[i]);
  } else {
    const int idx  = (blk & 63) * 256 + tid;         // 16384 elements
    const int gp   = idx >> 11;
    const int mrow = (idx >> 6) & 31;
    const int c    = idx & 63;
    const float val = mrow < 18 ? w2[(gp * 18 + mrow) * 64 + c] : 0.f;
    if (blk < 128) w2p[idx]  = f2bf(val);
    else           w2pr[idx] = f2bf(val - bf2f(f2bf(val)));
  }
}

// ---------------------------------------------------------------------------
// K1 (round-1 verified): 1x1 conv 256->64 as bf16 MFMA GEMM.
// Block 256 = 4 waves; wave = 16 px x 64 outputs. K-loop unrolled by 2
// (24 loads in flight). Grid: 8 * 256 = 2048 blocks.
// ---------------------------------------------------------------------------
__global__ __launch_bounds__(256) void k_conv1_mfma(const float* __restrict__ x,
                                                    const short* __restrict__ w1b,
                                                    const float* __restrict__ b1,
                                                    short* __restrict__ y1b) {
  const int blk  = blockIdx.x;          // b*256 + pixel-tile
  const int b    = blk >> 8;
  const int pt   = blk & 255;
  const int wave = threadIdx.x >> 6;
  const int lane = threadIdx.x & 63;
  const int quad = lane >> 4;
  const int l16  = lane & 15;
  const int p    = pt * 64 + wave * 16 + l16;

  const float* xb = x + (size_t)b * CIN * HW + p;

  floatx4 acc[4];
#pragma unroll
  for (int mt = 0; mt < 4; ++mt)
#pragma unroll
    for (int r = 0; r < 4; ++r) acc[mt][r] = b1[mt * 16 + quad * 4 + r];

#pragma unroll 1
  for (int kk = 0; kk < CIN; kk += 64) {
    short8 af0[4], af1[4];
#pragma unroll
    for (int mt = 0; mt < 4; ++mt) {
      af0[mt] = *(const short8*)(w1b + (mt * 16 + l16) * CIN + kk + quad * 8);
      af1[mt] = *(const short8*)(w1b + (mt * 16 + l16) * CIN + kk + 32 + quad * 8);
    }
    float xv0[8], xv1[8];
#pragma unroll
    for (int j = 0; j < 8; ++j)
      xv0[j] = xb[(size_t)(kk + quad * 8 + j) * HW];
#pragma unroll
    for (int j = 0; j < 8; ++j)
      xv1[j] = xb[(size_t)(kk + 32 + quad * 8 + j) * HW];

    short8 bf0, bf1;
#pragma unroll
    for (int j = 0; j < 8; ++j) bf0[j] = f2bf(xv0[j]);
#pragma unroll
    for (int j = 0; j < 8; ++j) bf1[j] = f2bf(xv1[j]);

#pragma unroll
    for (int mt = 0; mt < 4; ++mt)
      acc[mt] = __builtin_amdgcn_mfma_f32_16x16x32_bf16(af0[mt], bf0, acc[mt], 0, 0, 0);
#pragma unroll
    for (int mt = 0; mt < 4; ++mt)
      acc[mt] = __builtin_amdgcn_mfma_f32_16x16x32_bf16(af1[mt], bf1, acc[mt], 0, 0, 0);
  }

  short* yb = y1b + (size_t)b * CR * HW + p;
#pragma unroll
  for (int mt = 0; mt < 4; ++mt)
#pragma unroll
    for (int r = 0; r < 4; ++r)
      yb[(size_t)(mt * 16 + quad * 4 + r) * HW] = f2bf(acc[mt][r]);
}

// ---------------------------------------------------------------------------
// K2 (round-1 verified): depthwise 3x3 over y1b (bf16 in/out), zero pad 1.
// Thread = 2 rows x 8 cols (short8 loads/stores). Grid 2048.
// ---------------------------------------------------------------------------
__global__ __launch_bounds__(256) void k_dw(const short* __restrict__ y1b,
                                            const float* __restrict__ wd,
                                            const float* __restrict__ bd,
                                            short* __restrict__ y2b) {
  const int blk   = blockIdx.x;         // ((b*64 + c)*4 + strip)
  const int strip = blk & 3;
  const int c     = (blk >> 2) & 63;
  const int b     = blk >> 8;
  const int tcol  = threadIdx.x & 15;
  const int trow  = threadIdx.x >> 4;
  const int r0    = strip * 32 + trow * 2;
  const int c0    = tcol * 8;

  const short* src = y1b + (size_t)(b * CR + c) * HW;

  const float mcl = c0 > 0 ? 1.f : 0.f;
  const float mcr = c0 + 8 < IMW ? 1.f : 0.f;
  const int   cl  = c0 > 0 ? c0 - 1 : 0;
  const int   crr = c0 + 8 < IMW ? c0 + 8 : IMW - 1;

  float f[4][10];
#pragma unroll
  for (int i = 0; i < 4; ++i) {
    const int rr = r0 - 1 + i;
    const int rc = rr < 0 ? 0 : (rr > IMH - 1 ? IMH - 1 : rr);
    const float mr = (rr < 0 || rr > IMH - 1) ? 0.f : 1.f;
    const short* row = src + rc * IMW;
    const short8 v = *(const short8*)(row + c0);
#pragma unroll
    for (int j = 0; j < 8; ++j) f[i][j + 1] = mr * bf2f(v[j]);
    f[i][0] = mr * mcl * bf2f(row[cl]);
    f[i][9] = mr * mcr * bf2f(row[crr]);
  }

  float wv[9];
#pragma unroll
  for (int j = 0; j < 9; ++j) wv[j] = wd[c * 9 + j];
  const float bias = bd[c];

  short* dst = y2b + (size_t)(b * CR + c) * HW + r0 * IMW + c0;
#pragma unroll
  for (int i = 0; i < 2; ++i) {
    short8 o;
#pragma unroll
    for (int xcol = 0; xcol < 8; ++xcol) {
      float acc = bias;
#pragma unroll
      for (int kh = 0; kh < 3; ++kh)
#pragma unroll
        for (int kw = 0; kw < 3; ++kw)
          acc += wv[kh * 3 + kw] * f[i + kh][xcol + kw];
      o[xcol] = f2bf(acc);
    }
    *(short8*)(dst + i * IMW) = o;
  }
}

// ---------------------------------------------------------------------------
// K3: fused conv2 + involution, MFMA phase 1. Structure = round-4 verified
// (8x32 px tile, 2 groups/block, grid 4096); ONLY phase 1 changed:
//
// Phase 1 (MFMA): the block's 18 weight rows (2 groups x 9 taps) for its
// 256 px: wgt[18][256] = (w2p + w2pr)[18x64] * y2[64 x 256px] + b2, via
// 16x16x32 bf16 MFMA (M padded to 32 with zero rows; residual pass gives
// fp32-grade w2 — verified r3). Wave = 2 rows x 32 cols = 4 px-tiles of 16.
// LDS 18 KB (vs r3's 36), so ~2x the occupancy of the r3 attempt.
// Replaces 1152 serial VALU FMA/thread (~60 us of VALU issue) with
// 32 MFMA/wave.
//
// Phase 2: identical to round-4 verified streaming involution; wv comes
// from LDS (stride-1, 2-way = conflict-free).
// ---------------------------------------------------------------------------
__global__ __launch_bounds__(256) void k_conv2invol(const float* __restrict__ x,
                                                    const short* __restrict__ y2b,
                                                    const short* __restrict__ w2p,
                                                    const short* __restrict__ w2pr,
                                                    const float* __restrict__ b2,
                                                    float* __restrict__ out) {
  __shared__ float wgt[18 * 256];       // 18 KB
  const int blk  = blockIdx.x;          // (b*8 + gp)*64 + tile
  const int tile = blk & 63;            // 16 row-tiles x 4 col-tiles
  const int gp   = (blk >> 6) & 7;
  const int b    = blk >> 9;
  const int g0   = gp * 2;
  const int tid  = threadIdx.x;
  const int wave = tid >> 6;
  const int lane = tid & 63;
  const int quad = lane >> 4;
  const int l16  = lane & 15;
  const int h0   = (tile >> 2) * 8;
  const int w0   = (tile & 3) * 32;

  // ---- phase 1: 18 weight rows for 256 px via MFMA ----
  {
    const short* y2base = y2b + (size_t)b * CR * HW;
    int pabs[4];                        // wave owns rows 2w..2w+1, 4 16-px tiles
#pragma unroll
    for (int t = 0; t < 4; ++t)
      pabs[t] = (h0 + 2 * wave + (t >> 1)) * IMW + w0 + (t & 1) * 16 + l16;

    floatx4 acc[2][4];
#pragma unroll
    for (int mt = 0; mt < 2; ++mt)
#pragma unroll
      for (int t = 0; t < 4; ++t)
#pragma unroll
        for (int r = 0; r < 4; ++r) {
          const int row = mt * 16 + quad * 4 + r;
          acc[mt][t][r] = row < 18 ? b2[gp * 18 + row] : 0.f;
        }

#pragma unroll
    for (int kk = 0; kk < CR; kk += 32) {
      short8 bfrag[4];
#pragma unroll
      for (int t = 0; t < 4; ++t)
#pragma unroll
        for (int j = 0; j < 8; ++j)
          bfrag[t][j] = y2base[(size_t)(kk + quad * 8 + j) * HW + pabs[t]];
#pragma unroll
      for (int mt = 0; mt < 2; ++mt) {
        const short8 am = *(const short8*)(w2p + (gp * 32 + mt * 16 + l16) * 64 + kk + quad * 8);
#pragma unroll
        for (int t = 0; t < 4; ++t)
          acc[mt][t] = __builtin_amdgcn_mfma_f32_16x16x32_bf16(am, bfrag[t], acc[mt][t], 0, 0, 0);
      }
#pragma unroll
      for (int mt = 0; mt < 2; ++mt) {
        const short8 ar = *(const short8*)(w2pr + (gp * 32 + mt * 16 + l16) * 64 + kk + quad * 8);
#pragma unroll
        for (int t = 0; t < 4; ++t)
          acc[mt][t] = __builtin_amdgcn_mfma_f32_16x16x32_bf16(ar, bfrag[t], acc[mt][t], 0, 0, 0);
      }
    }

#pragma unroll
    for (int mt = 0; mt < 2; ++mt)
#pragma unroll
      for (int t = 0; t < 4; ++t) {
        const int pxl = (2 * wave + (t >> 1)) * 32 + (t & 1) * 16 + l16;
#pragma unroll
        for (int r = 0; r < 4; ++r) {
          const int row = mt * 16 + quad * 4 + r;
          if (row < 18) wgt[row * 256 + pxl] = acc[mt][t][r];
        }
      }
  }
  __syncthreads();

  // ---- phase 2: involution (round-4 verified), wv from LDS ----
  const int tr = tid >> 5;             // 0..7
  const int tc = tid & 31;             // 0..31
  const int h  = h0 + tr;
  const int w  = w0 + tc;
  const int p  = h * IMW + w;

  float wv[2][9];
#pragma unroll
  for (int q = 0; q < 2; ++q)
#pragma unroll
    for (int j = 0; j < 9; ++j)
      wv[q][j] = wgt[(q * 9 + j) * 256 + tid];

  // fold borders into weights; clamped tap offsets
  const int   hcl[3] = {h > 0 ? h - 1 : 0, h, h < IMH - 1 ? h + 1 : IMH - 1};
  const int   wcl[3] = {w > 0 ? w - 1 : 0, w, w < IMW - 1 ? w + 1 : IMW - 1};
  const float mr[3]  = {h > 0 ? 1.f : 0.f, 1.f, h < IMH - 1 ? 1.f : 0.f};
  const float mc[3]  = {w > 0 ? 1.f : 0.f, 1.f, w < IMW - 1 ? 1.f : 0.f};
  int rel[9];
#pragma unroll
  for (int kh = 0; kh < 3; ++kh)
#pragma unroll
    for (int kw = 0; kw < 3; ++kw) {
      rel[kh * 3 + kw] = hcl[kh] * IMW + wcl[kw];
      const float m = mr[kh] * mc[kw];
      wv[0][kh * 3 + kw] *= m;
      wv[1][kh * 3 + kw] *= m;
    }

  const float* xb = x + (size_t)b * CIN * HW;
  float*       ob = out + (size_t)b * CIN * HW;

#pragma unroll
  for (int q = 0; q < 2; ++q) {
#pragma unroll 4
    for (int cc = 0; cc < GC; ++cc) {
      const int ch = (g0 + q) * GC + cc;
      const float* xp = xb + (size_t)ch * HW;
      float acc = 0.f;
#pragma unroll
      for (int j = 0; j < 9; ++j) acc += wv[q][j] * xp[rel[j]];
      ob[(size_t)ch * HW + p] = acc;
    }
  }
}

extern "C" void kernel_launch(void* const* d_in, const int* in_sizes, int n_in,
                              void* d_out, int out_size, void* d_ws, size_t ws_size,
                              hipStream_t stream) {
  const float* x  = (const float*)d_in[0];
  const float* w1 = (const float*)d_in[1];
  const float* b1 = (const float*)d_in[2];
  const float* wd = (const float*)d_in[3];
  const float* bd = (const float*)d_in[4];
  const float* w2 = (const float*)d_in[5];
  const float* b2 = (const float*)d_in[6];
  float* out = (float*)d_out;

  // ws layout (33.62 MB total == the footprint proven in rounds 0/1/3/4):
  //   0        : w2p  bf16 32 KB  (padded [8][32][64])
  //   32768    : w2pr bf16 32 KB
  //   65536    : y1b  bf16 16.78 MB   (dead after k_dw)
  //   16842752 : y2b  bf16 16.78 MB
  //   w1b bf16 32 KB OVERLAPS the start of y2b (r3-verified trick): written
  //   by k_cvt, read by k_conv1, then overwritten by k_dw's y2b stores.
  short* w2p  = (short*)d_ws;
  short* w2pr = (short*)((char*)d_ws + 32768);
  short* y1b  = (short*)((char*)d_ws + 65536);
  short* y2b  = (short*)((char*)d_ws + 65536 + 16777216);
  short* w1b  = y2b;

  k_cvt<<<dim3(192), dim3(256), 0, stream>>>(w1, w2, w1b, w2p, w2pr);
  k_conv1_mfma<<<dim3(2048), dim3(256), 0, stream>>>(x, w1b, b1, y1b);
  k_dw<<<dim3(2048), dim3(256), 0, stream>>>(y1b, wd, bd, y2b);
  k_conv2invol<<<dim3(4096), dim3(256), 0, stream>>>(x, y2b, w2p, w2pr, b2, out);
}

// Round 6
// 350.640 us; speedup vs baseline: 1.1031x; 1.1031x over previous
//
#include <hip/hip_runtime.h>
#include <hip/hip_bf16.h>

#define HW    16384   // 128*128
#define IMW   128
#define IMH   128
#define CIN   256
#define CR    64
#define G     16
#define GC    16

typedef __attribute__((ext_vector_type(8))) short short8;
typedef __attribute__((ext_vector_type(4))) float floatx4;

static __device__ __forceinline__ short f2bf(float f) {
  union { float f; unsigned u; } v; v.f = f;
  unsigned r = v.u + 0x7fffu + ((v.u >> 16) & 1u);   // RNE
  return (short)(r >> 16);
}
static __device__ __forceinline__ float bf2f(short s) {
  union { unsigned u; float f; } v; v.u = ((unsigned)(unsigned short)s) << 16;
  return v.f;
}

#define GLL16(g, l) __builtin_amdgcn_global_load_lds( \
    (const __attribute__((address_space(1))) void*)(g), \
    (__attribute__((address_space(3))) void*)(l), 16, 0, 0)

// ---------------------------------------------------------------------------
// K0 (round-0 verified): convert w1 (fp32 [64][256]) -> bf16. 64 blocks.
// ---------------------------------------------------------------------------
__global__ __launch_bounds__(256) void k_cvt_w1(const float* __restrict__ w1,
                                                short* __restrict__ w1b) {
  const int i = blockIdx.x * 256 + threadIdx.x;      // 16384 elements
  w1b[i] = f2bf(w1[i]);
}

// ---------------------------------------------------------------------------
// K1: 1x1 conv 256->64 as bf16 MFMA GEMM: y1 = w1[64x256] * x[256xHW].
// NEW: x staged through LDS via global_load_lds width=16. Per K-step the
// block stages a dense [32 k][64 px] fp32 tile (8 KB): each wave issues 2
// staging ops covering 4 k-rows x 64 px each (lane contributes 16 B,
// 4 KB per 256-thread staging instruction group) — replaces 16 strided
// scalar x-load instructions (4x64B segments each) per iter. B-fragments
// read from LDS; same f2bf on the same values -> bit-exact vs round 1.
// Block 256 = 4 waves; wave = 16 px x 64 outputs (4 M-tiles, 16x16x32).
// Grid: 8 * 256 = 2048 blocks. LDS 8 KB.
// ---------------------------------------------------------------------------
__global__ __launch_bounds__(256) void k_conv1_mfma(const float* __restrict__ x,
                                                    const short* __restrict__ w1b,
                                                    const float* __restrict__ b1,
                                                    short* __restrict__ y1b) {
  __shared__ float xs[2048];            // [32 k][64 px] fp32, 8 KB
  const int blk  = blockIdx.x;          // b*256 + pixel-tile
  const int b    = blk >> 8;
  const int pt   = blk & 255;
  const int tid  = threadIdx.x;
  const int wave = tid >> 6;
  const int lane = tid & 63;
  const int quad = lane >> 4;
  const int l16  = lane & 15;
  const int px0  = pt * 64;
  const int p    = px0 + wave * 16 + l16;

  const float* xb = x + (size_t)b * CIN * HW + px0;
  // staging coords: thread tid contributes x[kk + (tid>>4)][px0 + (tid&15)*4 ..+3]
  // wave w writes LDS floats [w*256, w*256+256) = k-rows [w*4, w*4+4) x 64 px
  // (GLL dest = wave-uniform base + lane*16B; layout check: w*256 + lane*4
  //  == (w*4 + (lane>>4))*64 + (lane&15)*4  ✓)
  const int krow = tid >> 4;            // 0..15
  const int scol = (tid & 15) * 4;      // 0..60

  floatx4 acc[4];
#pragma unroll
  for (int mt = 0; mt < 4; ++mt)
#pragma unroll
    for (int r = 0; r < 4; ++r) acc[mt][r] = b1[mt * 16 + quad * 4 + r];

#pragma unroll 1
  for (int kk = 0; kk < CIN; kk += 32) {
    GLL16(xb + (size_t)(kk + krow) * HW + scol,      xs + wave * 256);
    GLL16(xb + (size_t)(kk + 16 + krow) * HW + scol, xs + 1024 + wave * 256);
    __syncthreads();   // drains vmcnt -> whole [32][64] tile visible

    short8 af[4];
#pragma unroll
    for (int mt = 0; mt < 4; ++mt)
      af[mt] = *(const short8*)(w1b + (mt * 16 + l16) * CIN + kk + quad * 8);

    short8 bfrag;
#pragma unroll
    for (int j = 0; j < 8; ++j)
      bfrag[j] = f2bf(xs[(quad * 8 + j) * 64 + wave * 16 + l16]);

#pragma unroll
    for (int mt = 0; mt < 4; ++mt)
      acc[mt] = __builtin_amdgcn_mfma_f32_16x16x32_bf16(af[mt], bfrag, acc[mt], 0, 0, 0);
    __syncthreads();   // protect xs before next stage
  }

  short* yb = y1b + (size_t)b * CR * HW + p;
#pragma unroll
  for (int mt = 0; mt < 4; ++mt)
#pragma unroll
    for (int r = 0; r < 4; ++r)
      yb[(size_t)(mt * 16 + quad * 4 + r) * HW] = f2bf(acc[mt][r]);
}

// ---------------------------------------------------------------------------
// K2 (round-1 verified, unchanged as control): depthwise 3x3 over y1b
// (bf16 in/out), zero pad 1. Thread = 2 rows x 8 cols (short8). Grid 2048.
// ---------------------------------------------------------------------------
__global__ __launch_bounds__(256) void k_dw(const short* __restrict__ y1b,
                                            const float* __restrict__ wd,
                                            const float* __restrict__ bd,
                                            short* __restrict__ y2b) {
  const int blk   = blockIdx.x;         // ((b*64 + c)*4 + strip)
  const int strip = blk & 3;
  const int c     = (blk >> 2) & 63;
  const int b     = blk >> 8;
  const int tcol  = threadIdx.x & 15;
  const int trow  = threadIdx.x >> 4;
  const int r0    = strip * 32 + trow * 2;
  const int c0    = tcol * 8;

  const short* src = y1b + (size_t)(b * CR + c) * HW;

  const float mcl = c0 > 0 ? 1.f : 0.f;
  const float mcr = c0 + 8 < IMW ? 1.f : 0.f;
  const int   cl  = c0 > 0 ? c0 - 1 : 0;
  const int   crr = c0 + 8 < IMW ? c0 + 8 : IMW - 1;

  float f[4][10];
#pragma unroll
  for (int i = 0; i < 4; ++i) {
    const int rr = r0 - 1 + i;
    const int rc = rr < 0 ? 0 : (rr > IMH - 1 ? IMH - 1 : rr);
    const float mr = (rr < 0 || rr > IMH - 1) ? 0.f : 1.f;
    const short* row = src + rc * IMW;
    const short8 v = *(const short8*)(row + c0);
#pragma unroll
    for (int j = 0; j < 8; ++j) f[i][j + 1] = mr * bf2f(v[j]);
    f[i][0] = mr * mcl * bf2f(row[cl]);
    f[i][9] = mr * mcr * bf2f(row[crr]);
  }

  float wv[9];
#pragma unroll
  for (int j = 0; j < 9; ++j) wv[j] = wd[c * 9 + j];
  const float bias = bd[c];

  short* dst = y2b + (size_t)(b * CR + c) * HW + r0 * IMW + c0;
#pragma unroll
  for (int i = 0; i < 2; ++i) {
    short8 o;
#pragma unroll
    for (int xcol = 0; xcol < 8; ++xcol) {
      float acc = bias;
#pragma unroll
      for (int kh = 0; kh < 3; ++kh)
#pragma unroll
        for (int kw = 0; kw < 3; ++kw)
          acc += wv[kh * 3 + kw] * f[i + kh][xcol + kw];
      o[xcol] = f2bf(acc);
    }
    *(short8*)(dst + i * IMW) = o;
  }
}

// ---------------------------------------------------------------------------
// K3 (round-1 verified EXACT — best known at ~120 us; fusion refuted twice):
// fused conv2 (64->144) + involution. 8x32 px tile, 2 groups/block,
// phase-1 unroll 2, no LDS. Grid 4096.
// ---------------------------------------------------------------------------
__global__ __launch_bounds__(256) void k_conv2invol(const float* __restrict__ x,
                                                    const short* __restrict__ y2b,
                                                    const float* __restrict__ w2,
                                                    const float* __restrict__ b2,
                                                    float* __restrict__ out) {
  const int blk  = blockIdx.x;         // (b*8 + gp)*64 + tile
  const int tile = blk & 63;           // 16 row-tiles x 4 col-tiles
  const int gp   = (blk >> 6) & 7;
  const int b    = blk >> 9;
  const int g0   = gp * 2;
  const int tid  = threadIdx.x;
  const int tr   = tid >> 5;           // 0..7
  const int tc   = tid & 31;           // 0..31
  const int h    = (tile >> 2) * 8 + tr;
  const int w    = (tile & 3) * 32 + tc;
  const int p    = h * IMW + w;

  // ---- phase 1: dynamic weights for this pixel, groups g0, g0+1 ----
  float wv[2][9];
#pragma unroll
  for (int q = 0; q < 2; ++q)
#pragma unroll
    for (int j = 0; j < 9; ++j) wv[q][j] = b2[(g0 + q) * 9 + j];

  const short* y2p = y2b + (size_t)b * CR * HW + p;
#pragma unroll 2
  for (int c = 0; c < CR; c += 4) {
    const float v0 = bf2f(y2p[(size_t)(c + 0) * HW]);
    const float v1 = bf2f(y2p[(size_t)(c + 1) * HW]);
    const float v2 = bf2f(y2p[(size_t)(c + 2) * HW]);
    const float v3 = bf2f(y2p[(size_t)(c + 3) * HW]);
#pragma unroll
    for (int q = 0; q < 2; ++q)
#pragma unroll
      for (int j = 0; j < 9; ++j) {
        const float4 wq = *(const float4*)(w2 + ((g0 + q) * 9 + j) * CR + c); // uniform
        wv[q][j] += wq.x * v0 + wq.y * v1 + wq.z * v2 + wq.w * v3;
      }
  }

  // ---- fold borders into weights; clamped tap offsets ----
  const int   hcl[3] = {h > 0 ? h - 1 : 0, h, h < IMH - 1 ? h + 1 : IMH - 1};
  const int   wcl[3] = {w > 0 ? w - 1 : 0, w, w < IMW - 1 ? w + 1 : IMW - 1};
  const float mr[3]  = {h > 0 ? 1.f : 0.f, 1.f, h < IMH - 1 ? 1.f : 0.f};
  const float mc[3]  = {w > 0 ? 1.f : 0.f, 1.f, w < IMW - 1 ? 1.f : 0.f};
  int rel[9];
#pragma unroll
  for (int kh = 0; kh < 3; ++kh)
#pragma unroll
    for (int kw = 0; kw < 3; ++kw) {
      rel[kh * 3 + kw] = hcl[kh] * IMW + wcl[kw];
      const float m = mr[kh] * mc[kw];
      wv[0][kh * 3 + kw] *= m;
      wv[1][kh * 3 + kw] *= m;
    }

  // ---- phase 2: involution, branchless taps through L1 ----
  const float* xb = x + (size_t)b * CIN * HW;
  float*       ob = out + (size_t)b * CIN * HW;

#pragma unroll
  for (int q = 0; q < 2; ++q) {
#pragma unroll 4
    for (int cc = 0; cc < GC; ++cc) {
      const int ch = (g0 + q) * GC + cc;
      const float* xp = xb + (size_t)ch * HW;
      float acc = 0.f;
#pragma unroll
      for (int j = 0; j < 9; ++j) acc += wv[q][j] * xp[rel[j]];
      ob[(size_t)ch * HW + p] = acc;
    }
  }
}

extern "C" void kernel_launch(void* const* d_in, const int* in_sizes, int n_in,
                              void* d_out, int out_size, void* d_ws, size_t ws_size,
                              hipStream_t stream) {
  const float* x  = (const float*)d_in[0];
  const float* w1 = (const float*)d_in[1];
  const float* b1 = (const float*)d_in[2];
  const float* wd = (const float*)d_in[3];
  const float* bd = (const float*)d_in[4];
  const float* w2 = (const float*)d_in[5];
  const float* b2 = (const float*)d_in[6];
  float* out = (float*)d_out;

  // ws layout (33.62 MB, proven in rounds 0/1/3/4/5):
  //   w1b bf16 (32 KB, padded to 64 KB) | y1b bf16 16.78 MB | y2b bf16 16.78 MB
  short* w1b = (short*)d_ws;
  short* y1b = (short*)((char*)d_ws + 65536);
  short* y2b = y1b + (size_t)8 * CR * HW;

  k_cvt_w1<<<dim3(64), dim3(256), 0, stream>>>(w1, w1b);
  k_conv1_mfma<<<dim3(2048), dim3(256), 0, stream>>>(x, w1b, b1, y1b);
  k_dw<<<dim3(2048), dim3(256), 0, stream>>>(y1b, wd, bd, y2b);
  k_conv2invol<<<dim3(4096), dim3(256), 0, stream>>>(x, y2b, w2, b2, out);
}